// Round 19
// baseline (1673.639 us; speedup 1.0000x reference)
//
#include <hip/hip_runtime.h>
#include <hip/hip_bf16.h>

#define BIG 1e30f

typedef __attribute__((ext_vector_type(8))) short short8;
typedef __attribute__((ext_vector_type(4))) float f32x4;

__device__ __forceinline__ unsigned pk_bf16(float lo, float hi) {
    unsigned r;
    asm("v_cvt_pk_bf16_f32 %0, %1, %2" : "=v"(r) : "v"(lo), "v"(hi));
    return r;
}

__device__ __forceinline__ short8 make_frag(float4 a, float4 c) {
    union { unsigned u[4]; short8 s; } cv;
    cv.u[0] = pk_bf16(a.x, a.y);
    cv.u[1] = pk_bf16(a.z, a.w);
    cv.u[2] = pk_bf16(c.x, c.y);
    cv.u[3] = pk_bf16(c.z, c.w);
    return cv.s;
}

// lane l <- lane l-1; lane 0 <- oldv. (wave_shr:1 validated r7/r17)
__device__ __forceinline__ float dpp_shr1_old(float v, float oldv) {
    int o = __builtin_amdgcn_update_dpp(__float_as_int(oldv), __float_as_int(v),
                                        0x138, 0xf, 0xf, false);
    return __int_as_float(o);
}

// one step of the wave64 inclusive prefix-min ladder (r17-validated)
#define DPPMIN(v, ctrl, rm) do { \
    int _s = __builtin_amdgcn_update_dpp(__float_as_int(v), __float_as_int(v), \
                                         (ctrl), (rm), 0xf, false); \
    (v) = fminf((v), __int_as_float(_s)); } while (0)

// ====================== dtw_full: ROUND 17 VERBATIM ======================
__global__ __launch_bounds__(512, 1) void dtw_full(const float* __restrict__ x,
                                                   const float* __restrict__ y,
                                                   float* __restrict__ out)
{
    __shared__ unsigned short Dp[2][64][520];
    __shared__ float x2s[512], y2s[512];
    __shared__ float psum[64][65];

    const int b   = blockIdx.x;
    const int tid = threadIdx.x;
    const int w   = tid >> 6;
    const int l   = tid & 63;
    const int lr  = l & 15;
    const int lg  = l >> 4;

    const float* xb = x + (size_t)b * 512 * 64;
    const float* yb = y + (size_t)b * 512 * 64;

    {
        const float4* xr = reinterpret_cast<const float4*>(xb + (size_t)tid * 64);
        const float4* yr = reinterpret_cast<const float4*>(yb + (size_t)tid * 64);
        float sx = 0.f, sy = 0.f;
        #pragma unroll
        for (int q = 0; q < 16; ++q) {
            float4 vx = xr[q], vy = yr[q];
            sx += vx.x*vx.x + vx.y*vx.y + vx.z*vx.z + vx.w*vx.w;
            sy += vy.x*vy.x + vy.y*vy.y + vy.z*vy.z + vy.w*vy.w;
        }
        x2s[tid] = sx;
        y2s[tid] = sy;
    }
    __syncthreads();

    const int ntile = (w == 6) ? 2 : 1;
    float cs[2][16];

    auto produce = [&](int pp) {
        const int j0 = pp * 64;
        unsigned short (*DBw)[520] = Dp[pp & 1];
        #pragma unroll
        for (int it = 0; it < 2; ++it) {
            if (it < ntile) {
                const int rt = (it == 0) ? w : 7;
                short8 afr[4][2];
                #pragma unroll
                for (int mi = 0; mi < 4; ++mi)
                    #pragma unroll
                    for (int ks = 0; ks < 2; ++ks) {
                        const float* rp = xb + (size_t)(rt*64 + mi*16 + lr) * 64 + ks*32 + lg*8;
                        float4 a0 = *reinterpret_cast<const float4*>(rp);
                        float4 a1 = *reinterpret_cast<const float4*>(rp + 4);
                        afr[mi][ks] = make_frag(a0, a1);
                    }
                f32x4 acc[4][4] = {};
                #pragma unroll
                for (int ni = 0; ni < 4; ++ni) {
                    const float* rp = yb + (size_t)(j0 + ni*16 + lr) * 64 + lg*8;
                    float4 b0 = *reinterpret_cast<const float4*>(rp);
                    float4 b1 = *reinterpret_cast<const float4*>(rp + 4);
                    float4 b2 = *reinterpret_cast<const float4*>(rp + 32);
                    float4 b3 = *reinterpret_cast<const float4*>(rp + 36);
                    short8 bf0 = make_frag(b0, b1);
                    short8 bf1 = make_frag(b2, b3);
                    #pragma unroll
                    for (int mi = 0; mi < 4; ++mi) {
                        acc[mi][ni] = __builtin_amdgcn_mfma_f32_16x16x32_bf16(afr[mi][0], bf0, acc[mi][ni], 0, 0, 0);
                        acc[mi][ni] = __builtin_amdgcn_mfma_f32_16x16x32_bf16(afr[mi][1], bf1, acc[mi][ni], 0, 0, 0);
                    }
                }
                float4 x2q[4];
                #pragma unroll
                for (int mi = 0; mi < 4; ++mi)
                    x2q[mi] = *reinterpret_cast<const float4*>(&x2s[rt*64 + mi*16 + lg*4]);
                #pragma unroll
                for (int ni = 0; ni < 4; ++ni) {
                    float y2v = y2s[j0 + ni*16 + lr];
                    #pragma unroll
                    for (int mi = 0; mi < 4; ++mi) {
                        float dd0 = x2q[mi].x + y2v - 2.0f * acc[mi][ni][0];
                        float dd1 = x2q[mi].y + y2v - 2.0f * acc[mi][ni][1];
                        float dd2 = x2q[mi].z + y2v - 2.0f * acc[mi][ni][2];
                        float dd3 = x2q[mi].w + y2v - 2.0f * acc[mi][ni][3];
                        unsigned w0 = pk_bf16(dd0, dd1);
                        unsigned w1 = pk_bf16(dd2, dd3);
                        uint2 pw; pw.x = w0; pw.y = w1;
                        *reinterpret_cast<uint2*>(&DBw[ni*16 + lr][rt*64 + mi*16 + lg*4]) = pw;
                        float fa = __uint_as_float(w0 << 16);
                        float fb = __uint_as_float(w0 & 0xffff0000u);
                        float fc = __uint_as_float(w1 << 16);
                        float fd = __uint_as_float(w1 & 0xffff0000u);
                        float s4 = (fa + fb) + (fc + fd);
                        s4 += __shfl_xor(s4, 16);
                        cs[it][mi*4 + ni] = s4;
                    }
                }
            }
        }
    };

    if (w < 7) produce(0);

    float pR[8];
    #pragma unroll
    for (int r = 0; r < 8; ++r) pR[r] = BIG;
    float bnd  = BIG;
    float bigf = BIG;

    #pragma unroll 1
    for (int p = 0; p < 8; ++p) {
        if (w < 7) {
            #pragma unroll
            for (int it = 0; it < 2; ++it) {
                if (it < ntile) {
                    const int rt = (it == 0) ? w : 7;
                    #pragma unroll
                    for (int mi = 0; mi < 4; ++mi)
                        #pragma unroll
                        for (int ni = 0; ni < 4; ++ni)
                            if ((lg & 1) == 0)
                                psum[ni*16 + lr][rt*8 + mi*2 + (lg >> 1)] = cs[it][mi*4 + ni];
                }
            }
        }
        __syncthreads();

        if (w == 7) {
            __builtin_amdgcn_s_setprio(1);
            {
                float run = 0.f;
                #pragma unroll
                for (int g = 0; g < 64; ++g) {
                    float tmp = psum[l][g];
                    psum[l][g] = run;
                    run += tmp;
                }
            }
            const unsigned short* DB = &Dp[p & 1][0][0];
            uint4 dc  = *reinterpret_cast<const uint4*>(DB + l*8);
            float pex = psum[0][l];
            #pragma unroll 1
            for (int cl = 0; cl < 64; ++cl) {
                const int cln = (cl < 63) ? cl + 1 : 63;
                uint4 dcn  = *reinterpret_cast<const uint4*>(DB + cln*520 + l*8);
                float pexn = psum[cln][l];

                float d[8], s[8], S[8], f[8], t[8], u1[8], u2[8], q[8];
                d[0] = __uint_as_float(dc.x << 16);
                d[1] = __uint_as_float(dc.x & 0xffff0000u);
                d[2] = __uint_as_float(dc.y << 16);
                d[3] = __uint_as_float(dc.y & 0xffff0000u);
                d[4] = __uint_as_float(dc.z << 16);
                d[5] = __uint_as_float(dc.z & 0xffff0000u);
                d[6] = __uint_as_float(dc.w << 16);
                d[7] = __uint_as_float(dc.w & 0xffff0000u);
                s[0] = d[0];
                #pragma unroll
                for (int r = 1; r < 8; ++r) s[r] = s[r-1] + d[r];
                #pragma unroll
                for (int r = 0; r < 8; ++r) S[r] = pex + s[r];

                float cz  = (p == 0 && cl == 0) ? 0.0f : BIG;
                float b0v = (l == 0) ? cz : bnd;
                f[0] = fminf(b0v, pR[0]);
                #pragma unroll
                for (int r = 1; r < 8; ++r) f[r] = fminf(pR[r-1], pR[r]);
                t[0] = f[0] - pex;
                #pragma unroll
                for (int r = 1; r < 8; ++r) t[r] = f[r] - S[r-1];

                u1[0] = t[0];
                #pragma unroll
                for (int r = 1; r < 8; ++r) u1[r] = fminf(t[r], t[r-1]);
                #pragma unroll
                for (int r = 0; r < 8; ++r) u2[r] = (r >= 2) ? fminf(u1[r], u1[r-2]) : u1[r];
                #pragma unroll
                for (int r = 0; r < 8; ++r) q[r]  = (r >= 4) ? fminf(u2[r], u2[r-4]) : u2[r];

                float v = q[7];
                DPPMIN(v, 0x111, 0xf);
                DPPMIN(v, 0x112, 0xf);
                DPPMIN(v, 0x114, 0xf);
                DPPMIN(v, 0x118, 0xf);
                DPPMIN(v, 0x142, 0xa);
                DPPMIN(v, 0x143, 0xc);
                float e = dpp_shr1_old(v, bigf);

                #pragma unroll
                for (int r = 0; r < 8; ++r) {
                    float m  = fminf(e, q[r]);
                    float Rv = S[r] + m;
                    pR[r] = Rv;
                }
                bnd = dpp_shr1_old(pR[7], pR[7]);
                dc = dcn; pex = pexn;
            }
            __builtin_amdgcn_s_setprio(0);
        } else if (p < 7) {
            produce(p + 1);
        }
        __syncthreads();
    }

    if (w == 7 && l == 63) out[b] = pR[7];
}

// ============== ablation body: MODE 1 = scan x8, MODE 2 = produce x8 ==============
template<int MODE>
__device__ void abl_body(const float* __restrict__ x, const float* __restrict__ y,
                         float* __restrict__ ws, unsigned wsn)
{
    __shared__ unsigned short Dp[2][64][520];
    __shared__ float x2s[512], y2s[512];
    __shared__ float psum[64][65];

    const int b   = blockIdx.x;
    const int tid = threadIdx.x;
    const int w   = tid >> 6;
    const int l   = tid & 63;
    const int lr  = l & 15;
    const int lg  = l >> 4;

    const float* xb = x + (size_t)b * 512 * 64;
    const float* yb = y + (size_t)b * 512 * 64;

    {
        const float4* xr = reinterpret_cast<const float4*>(xb + (size_t)tid * 64);
        const float4* yr = reinterpret_cast<const float4*>(yb + (size_t)tid * 64);
        float sx = 0.f, sy = 0.f;
        #pragma unroll
        for (int q = 0; q < 16; ++q) {
            float4 vx = xr[q], vy = yr[q];
            sx += vx.x*vx.x + vx.y*vx.y + vx.z*vx.z + vx.w*vx.w;
            sy += vy.x*vy.x + vy.y*vy.y + vy.z*vy.z + vy.w*vy.w;
        }
        x2s[tid] = sx;
        y2s[tid] = sy;
    }
    if (MODE == 1) {   // deterministic, NaN-free Dp for the scan-only mode
        for (int i = tid; i < 2*64*520; i += 512)
            (&Dp[0][0][0])[i] = 0;
    }
    __syncthreads();

    const int ntile = (w == 6) ? 2 : 1;
    float cs[2][16] = {};

    auto produce = [&](int pp) {
        const int j0 = pp * 64;
        unsigned short (*DBw)[520] = Dp[pp & 1];
        #pragma unroll
        for (int it = 0; it < 2; ++it) {
            if (it < ntile) {
                const int rt = (it == 0) ? w : 7;
                short8 afr[4][2];
                #pragma unroll
                for (int mi = 0; mi < 4; ++mi)
                    #pragma unroll
                    for (int ks = 0; ks < 2; ++ks) {
                        const float* rp = xb + (size_t)(rt*64 + mi*16 + lr) * 64 + ks*32 + lg*8;
                        float4 a0 = *reinterpret_cast<const float4*>(rp);
                        float4 a1 = *reinterpret_cast<const float4*>(rp + 4);
                        afr[mi][ks] = make_frag(a0, a1);
                    }
                f32x4 acc[4][4] = {};
                #pragma unroll
                for (int ni = 0; ni < 4; ++ni) {
                    const float* rp = yb + (size_t)(j0 + ni*16 + lr) * 64 + lg*8;
                    float4 b0 = *reinterpret_cast<const float4*>(rp);
                    float4 b1 = *reinterpret_cast<const float4*>(rp + 4);
                    float4 b2 = *reinterpret_cast<const float4*>(rp + 32);
                    float4 b3 = *reinterpret_cast<const float4*>(rp + 36);
                    short8 bf0 = make_frag(b0, b1);
                    short8 bf1 = make_frag(b2, b3);
                    #pragma unroll
                    for (int mi = 0; mi < 4; ++mi) {
                        acc[mi][ni] = __builtin_amdgcn_mfma_f32_16x16x32_bf16(afr[mi][0], bf0, acc[mi][ni], 0, 0, 0);
                        acc[mi][ni] = __builtin_amdgcn_mfma_f32_16x16x32_bf16(afr[mi][1], bf1, acc[mi][ni], 0, 0, 0);
                    }
                }
                float4 x2q[4];
                #pragma unroll
                for (int mi = 0; mi < 4; ++mi)
                    x2q[mi] = *reinterpret_cast<const float4*>(&x2s[rt*64 + mi*16 + lg*4]);
                #pragma unroll
                for (int ni = 0; ni < 4; ++ni) {
                    float y2v = y2s[j0 + ni*16 + lr];
                    #pragma unroll
                    for (int mi = 0; mi < 4; ++mi) {
                        float dd0 = x2q[mi].x + y2v - 2.0f * acc[mi][ni][0];
                        float dd1 = x2q[mi].y + y2v - 2.0f * acc[mi][ni][1];
                        float dd2 = x2q[mi].z + y2v - 2.0f * acc[mi][ni][2];
                        float dd3 = x2q[mi].w + y2v - 2.0f * acc[mi][ni][3];
                        unsigned w0 = pk_bf16(dd0, dd1);
                        unsigned w1 = pk_bf16(dd2, dd3);
                        uint2 pw; pw.x = w0; pw.y = w1;
                        *reinterpret_cast<uint2*>(&DBw[ni*16 + lr][rt*64 + mi*16 + lg*4]) = pw;
                        float fa = __uint_as_float(w0 << 16);
                        float fb = __uint_as_float(w0 & 0xffff0000u);
                        float fc = __uint_as_float(w1 << 16);
                        float fd = __uint_as_float(w1 & 0xffff0000u);
                        float s4 = (fa + fb) + (fc + fd);
                        s4 += __shfl_xor(s4, 16);
                        cs[it][mi*4 + ni] = s4;
                    }
                }
            }
        }
    };

    if (MODE == 2) { if (w < 7) produce(0); }

    float pR[8];
    #pragma unroll
    for (int r = 0; r < 8; ++r) pR[r] = BIG;
    float bnd = BIG, bigf = BIG;

    #pragma unroll 1
    for (int rep = 0; rep < 8; ++rep) {
        #pragma unroll 1
        for (int p = 0; p < 8; ++p) {
            if (w < 7) {
                #pragma unroll
                for (int it = 0; it < 2; ++it)
                    if (it < ntile) {
                        const int rt = (it == 0) ? w : 7;
                        #pragma unroll
                        for (int mi = 0; mi < 4; ++mi)
                            #pragma unroll
                            for (int ni = 0; ni < 4; ++ni)
                                if ((lg & 1) == 0)
                                    psum[ni*16 + lr][rt*8 + mi*2 + (lg >> 1)] = cs[it][mi*4 + ni];
                    }
            }
            __syncthreads();

            if (w == 7) {
                if (MODE == 1) {
                    __builtin_amdgcn_s_setprio(1);
                    {
                        float run = 0.f;
                        #pragma unroll
                        for (int g = 0; g < 64; ++g) {
                            float tmp = psum[l][g];
                            psum[l][g] = run;
                            run += tmp;
                        }
                    }
                    const unsigned short* DB = &Dp[p & 1][0][0];
                    uint4 dc  = *reinterpret_cast<const uint4*>(DB + l*8);
                    float pex = psum[0][l];
                    #pragma unroll 1
                    for (int cl = 0; cl < 64; ++cl) {
                        const int cln = (cl < 63) ? cl + 1 : 63;
                        uint4 dcn  = *reinterpret_cast<const uint4*>(DB + cln*520 + l*8);
                        float pexn = psum[cln][l];

                        float d[8], s[8], S[8], f[8], t[8], u1[8], u2[8], q[8];
                        d[0] = __uint_as_float(dc.x << 16);
                        d[1] = __uint_as_float(dc.x & 0xffff0000u);
                        d[2] = __uint_as_float(dc.y << 16);
                        d[3] = __uint_as_float(dc.y & 0xffff0000u);
                        d[4] = __uint_as_float(dc.z << 16);
                        d[5] = __uint_as_float(dc.z & 0xffff0000u);
                        d[6] = __uint_as_float(dc.w << 16);
                        d[7] = __uint_as_float(dc.w & 0xffff0000u);
                        s[0] = d[0];
                        #pragma unroll
                        for (int r = 1; r < 8; ++r) s[r] = s[r-1] + d[r];
                        #pragma unroll
                        for (int r = 0; r < 8; ++r) S[r] = pex + s[r];

                        float cz  = (p == 0 && cl == 0 && rep == 0) ? 0.0f : BIG;
                        float b0v = (l == 0) ? cz : bnd;
                        f[0] = fminf(b0v, pR[0]);
                        #pragma unroll
                        for (int r = 1; r < 8; ++r) f[r] = fminf(pR[r-1], pR[r]);
                        t[0] = f[0] - pex;
                        #pragma unroll
                        for (int r = 1; r < 8; ++r) t[r] = f[r] - S[r-1];

                        u1[0] = t[0];
                        #pragma unroll
                        for (int r = 1; r < 8; ++r) u1[r] = fminf(t[r], t[r-1]);
                        #pragma unroll
                        for (int r = 0; r < 8; ++r) u2[r] = (r >= 2) ? fminf(u1[r], u1[r-2]) : u1[r];
                        #pragma unroll
                        for (int r = 0; r < 8; ++r) q[r]  = (r >= 4) ? fminf(u2[r], u2[r-4]) : u2[r];

                        float v = q[7];
                        DPPMIN(v, 0x111, 0xf);
                        DPPMIN(v, 0x112, 0xf);
                        DPPMIN(v, 0x114, 0xf);
                        DPPMIN(v, 0x118, 0xf);
                        DPPMIN(v, 0x142, 0xa);
                        DPPMIN(v, 0x143, 0xc);
                        float e = dpp_shr1_old(v, bigf);

                        #pragma unroll
                        for (int r = 0; r < 8; ++r) pR[r] = S[r] + fminf(e, q[r]);
                        bnd = dpp_shr1_old(pR[7], pR[7]);
                        dc = dcn; pex = pexn;
                    }
                    __builtin_amdgcn_s_setprio(0);
                }
            } else if (p < 7) {
                if (MODE == 2) produce(p + 1);
            }
            __syncthreads();
        }
    }

    if (w == 7 && l == 63 && (unsigned)((b + 1) * 4) <= wsn) ws[b] = pR[7];
}

__global__ __launch_bounds__(512, 1) void dtw_scan8(const float* __restrict__ x,
                                                    const float* __restrict__ y,
                                                    float* __restrict__ ws, unsigned wsn) {
    abl_body<1>(x, y, ws, wsn);
}
__global__ __launch_bounds__(512, 1) void dtw_prod8(const float* __restrict__ x,
                                                    const float* __restrict__ y,
                                                    float* __restrict__ ws, unsigned wsn) {
    abl_body<2>(x, y, ws, wsn);
}

extern "C" void kernel_launch(void* const* d_in, const int* in_sizes, int n_in,
                              void* d_out, int out_size, void* d_ws, size_t ws_size,
                              hipStream_t stream) {
    (void)in_sizes; (void)n_in; (void)out_size;
    const float* x = (const float*)d_in[0];
    const float* y = (const float*)d_in[1];
    float* out = (float*)d_out;
    float* ws  = (float*)d_ws;
    unsigned wsn = (unsigned)(ws_size > 0xFFFFFFFFu ? 0xFFFFFFFFu : ws_size);

    dtw_full<<<128, 512, 0, stream>>>(x, y, out);        // real result (r17 verbatim)
    dtw_scan8<<<128, 512, 0, stream>>>(x, y, ws, wsn);   // 8 x scan share
    dtw_prod8<<<128, 512, 0, stream>>>(x, y, ws, wsn);   // 8 x producer share
}

// Round 20
// 142.640 us; speedup vs baseline: 11.7333x; 11.7333x over previous
//
#include <hip/hip_runtime.h>
#include <hip/hip_bf16.h>

#define BIG 1e30f

typedef __attribute__((ext_vector_type(8))) short short8;
typedef __attribute__((ext_vector_type(4))) float f32x4;

__device__ __forceinline__ unsigned pk_bf16(float lo, float hi) {
    unsigned r;
    asm("v_cvt_pk_bf16_f32 %0, %1, %2" : "=v"(r) : "v"(lo), "v"(hi));
    return r;
}

__device__ __forceinline__ short8 make_frag(float4 a, float4 c) {
    union { unsigned u[4]; short8 s; } cv;
    cv.u[0] = pk_bf16(a.x, a.y);
    cv.u[1] = pk_bf16(a.z, a.w);
    cv.u[2] = pk_bf16(c.x, c.y);
    cv.u[3] = pk_bf16(c.z, c.w);
    return cv.s;
}

// lane l <- lane l-1; lane 0 <- oldv. (wave_shr:1 validated r7/r17)
__device__ __forceinline__ float dpp_shr1_old(float v, float oldv) {
    int o = __builtin_amdgcn_update_dpp(__float_as_int(oldv), __float_as_int(v),
                                        0x138, 0xf, 0xf, false);
    return __int_as_float(o);
}

// one step of the wave64 inclusive prefix-min ladder (r17-validated)
#define DPPMIN(v, ctrl, rm) do { \
    int _s = __builtin_amdgcn_update_dpp(__float_as_int(v), __float_as_int(v), \
                                         (ctrl), (rm), 0xf, false); \
    (v) = fminf((v), __int_as_float(_s)); } while (0)

// ROUND 20 = r17/r19 dtw_full with exactly two scan-side changes, no template
// siblings (r19 ablation: scan = 124.5us of the 146us wall, issue-bound +
// 25us serial psum prefix):
//  (a) vectorized psum exclusive prefix (psum[64][68], b128 loads, register
//      scan, b128 stores) replacing the 64-step serial LDS RMW loop;
//  (b) column chain issue cut: direct S build (8 adds) + serial-fmin prefix
//      (7 fmin) replacing s[]/S[] (16 adds) + 17-op Hillis. Same math.
// Producers, loop structure, prefetch, DPP ladder: verbatim.
__global__ __launch_bounds__(512, 1) void dtw_full(const float* __restrict__ x,
                                                   const float* __restrict__ y,
                                                   float* __restrict__ out)
{
    __shared__ unsigned short Dp[2][64][520];
    __shared__ float x2s[512], y2s[512];
    __shared__ float psum[64][68];     // row stride 272B: 16B-aligned for b128

    const int b   = blockIdx.x;
    const int tid = threadIdx.x;
    const int w   = tid >> 6;
    const int l   = tid & 63;
    const int lr  = l & 15;
    const int lg  = l >> 4;

    const float* xb = x + (size_t)b * 512 * 64;
    const float* yb = y + (size_t)b * 512 * 64;

    {
        const float4* xr = reinterpret_cast<const float4*>(xb + (size_t)tid * 64);
        const float4* yr = reinterpret_cast<const float4*>(yb + (size_t)tid * 64);
        float sx = 0.f, sy = 0.f;
        #pragma unroll
        for (int q = 0; q < 16; ++q) {
            float4 vx = xr[q], vy = yr[q];
            sx += vx.x*vx.x + vx.y*vx.y + vx.z*vx.z + vx.w*vx.w;
            sy += vy.x*vy.x + vy.y*vy.y + vy.z*vy.z + vy.w*vy.w;
        }
        x2s[tid] = sx;
        y2s[tid] = sy;
    }
    __syncthreads();

    const int ntile = (w == 6) ? 2 : 1;
    float cs[2][16];

    auto produce = [&](int pp) {
        const int j0 = pp * 64;
        unsigned short (*DBw)[520] = Dp[pp & 1];
        #pragma unroll
        for (int it = 0; it < 2; ++it) {
            if (it < ntile) {
                const int rt = (it == 0) ? w : 7;
                short8 afr[4][2];
                #pragma unroll
                for (int mi = 0; mi < 4; ++mi)
                    #pragma unroll
                    for (int ks = 0; ks < 2; ++ks) {
                        const float* rp = xb + (size_t)(rt*64 + mi*16 + lr) * 64 + ks*32 + lg*8;
                        float4 a0 = *reinterpret_cast<const float4*>(rp);
                        float4 a1 = *reinterpret_cast<const float4*>(rp + 4);
                        afr[mi][ks] = make_frag(a0, a1);
                    }
                f32x4 acc[4][4] = {};
                #pragma unroll
                for (int ni = 0; ni < 4; ++ni) {
                    const float* rp = yb + (size_t)(j0 + ni*16 + lr) * 64 + lg*8;
                    float4 b0 = *reinterpret_cast<const float4*>(rp);
                    float4 b1 = *reinterpret_cast<const float4*>(rp + 4);
                    float4 b2 = *reinterpret_cast<const float4*>(rp + 32);
                    float4 b3 = *reinterpret_cast<const float4*>(rp + 36);
                    short8 bf0 = make_frag(b0, b1);
                    short8 bf1 = make_frag(b2, b3);
                    #pragma unroll
                    for (int mi = 0; mi < 4; ++mi) {
                        acc[mi][ni] = __builtin_amdgcn_mfma_f32_16x16x32_bf16(afr[mi][0], bf0, acc[mi][ni], 0, 0, 0);
                        acc[mi][ni] = __builtin_amdgcn_mfma_f32_16x16x32_bf16(afr[mi][1], bf1, acc[mi][ni], 0, 0, 0);
                    }
                }
                float4 x2q[4];
                #pragma unroll
                for (int mi = 0; mi < 4; ++mi)
                    x2q[mi] = *reinterpret_cast<const float4*>(&x2s[rt*64 + mi*16 + lg*4]);
                #pragma unroll
                for (int ni = 0; ni < 4; ++ni) {
                    float y2v = y2s[j0 + ni*16 + lr];
                    #pragma unroll
                    for (int mi = 0; mi < 4; ++mi) {
                        float dd0 = x2q[mi].x + y2v - 2.0f * acc[mi][ni][0];
                        float dd1 = x2q[mi].y + y2v - 2.0f * acc[mi][ni][1];
                        float dd2 = x2q[mi].z + y2v - 2.0f * acc[mi][ni][2];
                        float dd3 = x2q[mi].w + y2v - 2.0f * acc[mi][ni][3];
                        unsigned w0 = pk_bf16(dd0, dd1);
                        unsigned w1 = pk_bf16(dd2, dd3);
                        uint2 pw; pw.x = w0; pw.y = w1;
                        *reinterpret_cast<uint2*>(&DBw[ni*16 + lr][rt*64 + mi*16 + lg*4]) = pw;
                        float fa = __uint_as_float(w0 << 16);
                        float fb = __uint_as_float(w0 & 0xffff0000u);
                        float fc = __uint_as_float(w1 << 16);
                        float fd = __uint_as_float(w1 & 0xffff0000u);
                        float s4 = (fa + fb) + (fc + fd);
                        s4 += __shfl_xor(s4, 16);
                        cs[it][mi*4 + ni] = s4;
                    }
                }
            }
        }
    };

    if (w < 7) produce(0);

    float pR[8];
    #pragma unroll
    for (int r = 0; r < 8; ++r) pR[r] = BIG;
    float bnd  = BIG;
    float bigf = BIG;

    #pragma unroll 1
    for (int p = 0; p < 8; ++p) {
        if (w < 7) {
            #pragma unroll
            for (int it = 0; it < 2; ++it) {
                if (it < ntile) {
                    const int rt = (it == 0) ? w : 7;
                    #pragma unroll
                    for (int mi = 0; mi < 4; ++mi)
                        #pragma unroll
                        for (int ni = 0; ni < 4; ++ni)
                            if ((lg & 1) == 0)
                                psum[ni*16 + lr][rt*8 + mi*2 + (lg >> 1)] = cs[it][mi*4 + ni];
                }
            }
        }
        __syncthreads();

        if (w == 7) {
            __builtin_amdgcn_s_setprio(1);
            // (a) vectorized exclusive group-prefix per column (lane = column)
            {
                float4 v[16];
                #pragma unroll
                for (int q4 = 0; q4 < 16; ++q4)
                    v[q4] = *reinterpret_cast<const float4*>(&psum[l][q4*4]);
                float run = 0.f;
                #pragma unroll
                for (int q4 = 0; q4 < 16; ++q4) {
                    float a0 = v[q4].x, a1 = v[q4].y, a2 = v[q4].z, a3 = v[q4].w;
                    float r1s = run + a0, r2s = r1s + a1, r3s = r2s + a2;
                    v[q4].x = run; v[q4].y = r1s; v[q4].z = r2s; v[q4].w = r3s;
                    run = r3s + a3;
                }
                #pragma unroll
                for (int q4 = 0; q4 < 16; ++q4)
                    *reinterpret_cast<float4*>(&psum[l][q4*4]) = v[q4];
            }
            const unsigned short* DB = &Dp[p & 1][0][0];
            uint4 dc  = *reinterpret_cast<const uint4*>(DB + l*8);
            float pex = psum[0][l];
            #pragma unroll 1
            for (int cl = 0; cl < 64; ++cl) {
                const int cln = (cl < 63) ? cl + 1 : 63;
                uint4 dcn  = *reinterpret_cast<const uint4*>(DB + cln*520 + l*8);
                float pexn = psum[cln][l];

                // (b) direct S build: 8 adds
                float S0 = pex + __uint_as_float(dc.x << 16);
                float S1 = S0  + __uint_as_float(dc.x & 0xffff0000u);
                float S2 = S1  + __uint_as_float(dc.y << 16);
                float S3 = S2  + __uint_as_float(dc.y & 0xffff0000u);
                float S4 = S3  + __uint_as_float(dc.z << 16);
                float S5 = S4  + __uint_as_float(dc.z & 0xffff0000u);
                float S6 = S5  + __uint_as_float(dc.w << 16);
                float S7 = S6  + __uint_as_float(dc.w & 0xffff0000u);

                float cz  = (p == 0 && cl == 0) ? 0.0f : BIG;
                float b0v = (l == 0) ? cz : bnd;
                float t0 = fminf(b0v,  pR[0]) - pex;
                float t1 = fminf(pR[0], pR[1]) - S0;
                float t2 = fminf(pR[1], pR[2]) - S1;
                float t3 = fminf(pR[2], pR[3]) - S2;
                float t4 = fminf(pR[3], pR[4]) - S3;
                float t5 = fminf(pR[4], pR[5]) - S4;
                float t6 = fminf(pR[5], pR[6]) - S5;
                float t7 = fminf(pR[6], pR[7]) - S6;

                // (b) serial-fmin inclusive prefix (same math as Hillis)
                float q0 = t0;
                float q1 = fminf(t1, q0);
                float q2 = fminf(t2, q1);
                float q3 = fminf(t3, q2);
                float q4 = fminf(t4, q3);
                float q5 = fminf(t5, q4);
                float q6 = fminf(t6, q5);
                float q7 = fminf(t7, q6);

                float v = q7;
                DPPMIN(v, 0x111, 0xf);   // row_shr:1
                DPPMIN(v, 0x112, 0xf);   // row_shr:2
                DPPMIN(v, 0x114, 0xf);   // row_shr:4
                DPPMIN(v, 0x118, 0xf);   // row_shr:8
                DPPMIN(v, 0x142, 0xa);   // row_bcast:15
                DPPMIN(v, 0x143, 0xc);   // row_bcast:31
                float e = dpp_shr1_old(v, bigf);   // exclusive, lane0 = BIG

                pR[0] = S0 + fminf(e, q0);
                pR[1] = S1 + fminf(e, q1);
                pR[2] = S2 + fminf(e, q2);
                pR[3] = S3 + fminf(e, q3);
                pR[4] = S4 + fminf(e, q4);
                pR[5] = S5 + fminf(e, q5);
                pR[6] = S6 + fminf(e, q6);
                pR[7] = S7 + fminf(e, q7);
                bnd = dpp_shr1_old(pR[7], pR[7]);
                dc = dcn; pex = pexn;
            }
            __builtin_amdgcn_s_setprio(0);
        } else if (p < 7) {
            produce(p + 1);
        }
        __syncthreads();
    }

    if (w == 7 && l == 63) out[b] = pR[7];
}

extern "C" void kernel_launch(void* const* d_in, const int* in_sizes, int n_in,
                              void* d_out, int out_size, void* d_ws, size_t ws_size,
                              hipStream_t stream) {
    (void)in_sizes; (void)n_in; (void)d_ws; (void)ws_size; (void)out_size;
    const float* x = (const float*)d_in[0];
    const float* y = (const float*)d_in[1];
    float* out = (float*)d_out;
    dtw_full<<<128, 512, 0, stream>>>(x, y, out);
}

// Round 21
// 137.640 us; speedup vs baseline: 12.1595x; 1.0363x over previous
//
#include <hip/hip_runtime.h>
#include <hip/hip_bf16.h>

#define BIG 1e30f

typedef __attribute__((ext_vector_type(8))) short short8;
typedef __attribute__((ext_vector_type(4))) float f32x4;

__device__ __forceinline__ unsigned pk_bf16(float lo, float hi) {
    unsigned r;
    asm("v_cvt_pk_bf16_f32 %0, %1, %2" : "=v"(r) : "v"(lo), "v"(hi));
    return r;
}

__device__ __forceinline__ short8 make_frag(float4 a, float4 c) {
    union { unsigned u[4]; short8 s; } cv;
    cv.u[0] = pk_bf16(a.x, a.y);
    cv.u[1] = pk_bf16(a.z, a.w);
    cv.u[2] = pk_bf16(c.x, c.y);
    cv.u[3] = pk_bf16(c.z, c.w);
    return cv.s;
}

// lane l <- lane l-1; lane 0 <- oldv. (wave_shr:1 validated r7/r17)
__device__ __forceinline__ float dpp_shr1_old(float v, float oldv) {
    int o = __builtin_amdgcn_update_dpp(__float_as_int(oldv), __float_as_int(v),
                                        0x138, 0xf, 0xf, false);
    return __int_as_float(o);
}

// one step of the wave64 inclusive prefix-min ladder (r17-validated)
#define DPPMIN(v, ctrl, rm) do { \
    int _s = __builtin_amdgcn_update_dpp(__float_as_int(v), __float_as_int(v), \
                                         (ctrl), (rm), 0xf, false); \
    (v) = fminf((v), __int_as_float(_s)); } while (0)

// ROUND 21 = r20 (142.6us, absmax 256) + ONE change: pipelined S build.
// Column cl+1's serial 8-add S chain is computed during column cl's DPP
// chain (off the critical path), consuming dc/pex prefetched 2 columns
// ahead (full column of LDS latency cover). This is the single r18
// ingredient never tested alone (r20 validated the other two); standalone
// kernel, no template siblings -> attributable result either way.
__global__ __launch_bounds__(512, 1) void dtw_full(const float* __restrict__ x,
                                                   const float* __restrict__ y,
                                                   float* __restrict__ out)
{
    __shared__ unsigned short Dp[2][64][520];
    __shared__ float x2s[512], y2s[512];
    __shared__ float psum[64][68];     // row stride 272B: 16B-aligned for b128

    const int b   = blockIdx.x;
    const int tid = threadIdx.x;
    const int w   = tid >> 6;
    const int l   = tid & 63;
    const int lr  = l & 15;
    const int lg  = l >> 4;

    const float* xb = x + (size_t)b * 512 * 64;
    const float* yb = y + (size_t)b * 512 * 64;

    {
        const float4* xr = reinterpret_cast<const float4*>(xb + (size_t)tid * 64);
        const float4* yr = reinterpret_cast<const float4*>(yb + (size_t)tid * 64);
        float sx = 0.f, sy = 0.f;
        #pragma unroll
        for (int q = 0; q < 16; ++q) {
            float4 vx = xr[q], vy = yr[q];
            sx += vx.x*vx.x + vx.y*vx.y + vx.z*vx.z + vx.w*vx.w;
            sy += vy.x*vy.x + vy.y*vy.y + vy.z*vy.z + vy.w*vy.w;
        }
        x2s[tid] = sx;
        y2s[tid] = sy;
    }
    __syncthreads();

    const int ntile = (w == 6) ? 2 : 1;
    float cs[2][16];

    auto produce = [&](int pp) {
        const int j0 = pp * 64;
        unsigned short (*DBw)[520] = Dp[pp & 1];
        #pragma unroll
        for (int it = 0; it < 2; ++it) {
            if (it < ntile) {
                const int rt = (it == 0) ? w : 7;
                short8 afr[4][2];
                #pragma unroll
                for (int mi = 0; mi < 4; ++mi)
                    #pragma unroll
                    for (int ks = 0; ks < 2; ++ks) {
                        const float* rp = xb + (size_t)(rt*64 + mi*16 + lr) * 64 + ks*32 + lg*8;
                        float4 a0 = *reinterpret_cast<const float4*>(rp);
                        float4 a1 = *reinterpret_cast<const float4*>(rp + 4);
                        afr[mi][ks] = make_frag(a0, a1);
                    }
                f32x4 acc[4][4] = {};
                #pragma unroll
                for (int ni = 0; ni < 4; ++ni) {
                    const float* rp = yb + (size_t)(j0 + ni*16 + lr) * 64 + lg*8;
                    float4 b0 = *reinterpret_cast<const float4*>(rp);
                    float4 b1 = *reinterpret_cast<const float4*>(rp + 4);
                    float4 b2 = *reinterpret_cast<const float4*>(rp + 32);
                    float4 b3 = *reinterpret_cast<const float4*>(rp + 36);
                    short8 bf0 = make_frag(b0, b1);
                    short8 bf1 = make_frag(b2, b3);
                    #pragma unroll
                    for (int mi = 0; mi < 4; ++mi) {
                        acc[mi][ni] = __builtin_amdgcn_mfma_f32_16x16x32_bf16(afr[mi][0], bf0, acc[mi][ni], 0, 0, 0);
                        acc[mi][ni] = __builtin_amdgcn_mfma_f32_16x16x32_bf16(afr[mi][1], bf1, acc[mi][ni], 0, 0, 0);
                    }
                }
                float4 x2q[4];
                #pragma unroll
                for (int mi = 0; mi < 4; ++mi)
                    x2q[mi] = *reinterpret_cast<const float4*>(&x2s[rt*64 + mi*16 + lg*4]);
                #pragma unroll
                for (int ni = 0; ni < 4; ++ni) {
                    float y2v = y2s[j0 + ni*16 + lr];
                    #pragma unroll
                    for (int mi = 0; mi < 4; ++mi) {
                        float dd0 = x2q[mi].x + y2v - 2.0f * acc[mi][ni][0];
                        float dd1 = x2q[mi].y + y2v - 2.0f * acc[mi][ni][1];
                        float dd2 = x2q[mi].z + y2v - 2.0f * acc[mi][ni][2];
                        float dd3 = x2q[mi].w + y2v - 2.0f * acc[mi][ni][3];
                        unsigned w0 = pk_bf16(dd0, dd1);
                        unsigned w1 = pk_bf16(dd2, dd3);
                        uint2 pw; pw.x = w0; pw.y = w1;
                        *reinterpret_cast<uint2*>(&DBw[ni*16 + lr][rt*64 + mi*16 + lg*4]) = pw;
                        float fa = __uint_as_float(w0 << 16);
                        float fb = __uint_as_float(w0 & 0xffff0000u);
                        float fc = __uint_as_float(w1 << 16);
                        float fd = __uint_as_float(w1 & 0xffff0000u);
                        float s4 = (fa + fb) + (fc + fd);
                        s4 += __shfl_xor(s4, 16);
                        cs[it][mi*4 + ni] = s4;
                    }
                }
            }
        }
    };

    if (w < 7) produce(0);

    float pR[8];
    #pragma unroll
    for (int r = 0; r < 8; ++r) pR[r] = BIG;
    float bnd  = BIG;
    float bigf = BIG;

    #pragma unroll 1
    for (int p = 0; p < 8; ++p) {
        if (w < 7) {
            #pragma unroll
            for (int it = 0; it < 2; ++it) {
                if (it < ntile) {
                    const int rt = (it == 0) ? w : 7;
                    #pragma unroll
                    for (int mi = 0; mi < 4; ++mi)
                        #pragma unroll
                        for (int ni = 0; ni < 4; ++ni)
                            if ((lg & 1) == 0)
                                psum[ni*16 + lr][rt*8 + mi*2 + (lg >> 1)] = cs[it][mi*4 + ni];
                }
            }
        }
        __syncthreads();

        if (w == 7) {
            __builtin_amdgcn_s_setprio(1);
            // vectorized exclusive group-prefix per column (lane = column)
            {
                float4 v[16];
                #pragma unroll
                for (int q4 = 0; q4 < 16; ++q4)
                    v[q4] = *reinterpret_cast<const float4*>(&psum[l][q4*4]);
                float run = 0.f;
                #pragma unroll
                for (int q4 = 0; q4 < 16; ++q4) {
                    float a0 = v[q4].x, a1 = v[q4].y, a2 = v[q4].z, a3 = v[q4].w;
                    float r1s = run + a0, r2s = r1s + a1, r3s = r2s + a2;
                    v[q4].x = run; v[q4].y = r1s; v[q4].z = r2s; v[q4].w = r3s;
                    run = r3s + a3;
                }
                #pragma unroll
                for (int q4 = 0; q4 < 16; ++q4)
                    *reinterpret_cast<float4*>(&psum[l][q4*4]) = v[q4];
            }
            const unsigned short* DB = &Dp[p & 1][0][0];

            float S0, S1, S2, S3, S4, S5, S6, S7, P;
            auto buildS = [&](uint4 dc, float pex) {
                P  = pex;
                S0 = pex + __uint_as_float(dc.x << 16);
                S1 = S0  + __uint_as_float(dc.x & 0xffff0000u);
                S2 = S1  + __uint_as_float(dc.y << 16);
                S3 = S2  + __uint_as_float(dc.y & 0xffff0000u);
                S4 = S3  + __uint_as_float(dc.z << 16);
                S5 = S4  + __uint_as_float(dc.z & 0xffff0000u);
                S6 = S5  + __uint_as_float(dc.w << 16);
                S7 = S6  + __uint_as_float(dc.w & 0xffff0000u);
            };

            uint4 dcA  = *reinterpret_cast<const uint4*>(DB + l*8);
            float pexA = psum[0][l];
            uint4 dcB  = *reinterpret_cast<const uint4*>(DB + 520 + l*8);
            float pexB = psum[1][l];
            buildS(dcA, pexA);              // S for column 0

            #pragma unroll 1
            for (int cl = 0; cl < 64; ++cl) {
                const int cl2 = (cl < 62) ? cl + 2 : 63;
                uint4 dc2  = *reinterpret_cast<const uint4*>(DB + cl2*520 + l*8);
                float pex2 = psum[cl2][l];

                // ---- chain on current column's S (critical path) ----
                float cz  = (p == 0 && cl == 0) ? 0.0f : BIG;
                float b0v = (l == 0) ? cz : bnd;
                float t0 = fminf(b0v,  pR[0]) - P;
                float t1 = fminf(pR[0], pR[1]) - S0;
                float t2 = fminf(pR[1], pR[2]) - S1;
                float t3 = fminf(pR[2], pR[3]) - S2;
                float t4 = fminf(pR[3], pR[4]) - S3;
                float t5 = fminf(pR[4], pR[5]) - S4;
                float t6 = fminf(pR[5], pR[6]) - S5;
                float t7 = fminf(pR[6], pR[7]) - S6;

                float q0 = t0;
                float q1 = fminf(t1, q0);
                float q2 = fminf(t2, q1);
                float q3 = fminf(t3, q2);
                float q4 = fminf(t4, q3);
                float q5 = fminf(t5, q4);
                float q6 = fminf(t6, q5);
                float q7 = fminf(t7, q6);

                float v = q7;
                DPPMIN(v, 0x111, 0xf);   // row_shr:1
                DPPMIN(v, 0x112, 0xf);   // row_shr:2
                DPPMIN(v, 0x114, 0xf);   // row_shr:4
                DPPMIN(v, 0x118, 0xf);   // row_shr:8
                DPPMIN(v, 0x142, 0xa);   // row_bcast:15
                DPPMIN(v, 0x143, 0xc);   // row_bcast:31
                float e = dpp_shr1_old(v, bigf);   // exclusive, lane0 = BIG

                float nR0 = S0 + fminf(e, q0);
                float nR1 = S1 + fminf(e, q1);
                float nR2 = S2 + fminf(e, q2);
                float nR3 = S3 + fminf(e, q3);
                float nR4 = S4 + fminf(e, q4);
                float nR5 = S5 + fminf(e, q5);
                float nR6 = S6 + fminf(e, q6);
                float nR7 = S7 + fminf(e, q7);

                // ---- off-chain: next column's S; rotate prefetch ----
                buildS(dcB, pexB);
                dcB = dc2; pexB = pex2;

                pR[0] = nR0; pR[1] = nR1; pR[2] = nR2; pR[3] = nR3;
                pR[4] = nR4; pR[5] = nR5; pR[6] = nR6; pR[7] = nR7;
                bnd = dpp_shr1_old(nR7, nR7);
            }
            __builtin_amdgcn_s_setprio(0);
        } else if (p < 7) {
            produce(p + 1);
        }
        __syncthreads();
    }

    if (w == 7 && l == 63) out[b] = pR[7];
}

extern "C" void kernel_launch(void* const* d_in, const int* in_sizes, int n_in,
                              void* d_out, int out_size, void* d_ws, size_t ws_size,
                              hipStream_t stream) {
    (void)in_sizes; (void)n_in; (void)d_ws; (void)ws_size; (void)out_size;
    const float* x = (const float*)d_in[0];
    const float* y = (const float*)d_in[1];
    float* out = (float*)d_out;
    dtw_full<<<128, 512, 0, stream>>>(x, y, out);
}

// Round 22
// 134.282 us; speedup vs baseline: 12.4636x; 1.0250x over previous
//
#include <hip/hip_runtime.h>
#include <hip/hip_bf16.h>

#define BIG 1e30f

typedef __attribute__((ext_vector_type(8))) short short8;
typedef __attribute__((ext_vector_type(4))) float f32x4;

__device__ __forceinline__ unsigned pk_bf16(float lo, float hi) {
    unsigned r;
    asm("v_cvt_pk_bf16_f32 %0, %1, %2" : "=v"(r) : "v"(lo), "v"(hi));
    return r;
}

__device__ __forceinline__ short8 make_frag(float4 a, float4 c) {
    union { unsigned u[4]; short8 s; } cv;
    cv.u[0] = pk_bf16(a.x, a.y);
    cv.u[1] = pk_bf16(a.z, a.w);
    cv.u[2] = pk_bf16(c.x, c.y);
    cv.u[3] = pk_bf16(c.z, c.w);
    return cv.s;
}

// 3-input min; clang folds nested fminf into v_min3_f32 on gfx9+ (T17).
__device__ __forceinline__ float min3f(float a, float b, float c) {
    return fminf(fminf(a, b), c);
}

// lane l <- lane l-1; lane 0 <- oldv. (wave_shr:1 validated r7/r17)
__device__ __forceinline__ float dpp_shr1_old(float v, float oldv) {
    int o = __builtin_amdgcn_update_dpp(__float_as_int(oldv), __float_as_int(v),
                                        0x138, 0xf, 0xf, false);
    return __int_as_float(o);
}

// one step of the wave64 inclusive prefix-min ladder (r17-validated)
#define DPPMIN(v, ctrl, rm) do { \
    int _s = __builtin_amdgcn_update_dpp(__float_as_int(v), __float_as_int(v), \
                                         (ctrl), (rm), 0xf, false); \
    (v) = fminf((v), __int_as_float(_s)); } while (0)

// ROUND 22 = r21 (137.6us, absmax 256) + ONE change: the intra-lane q-prefix
// uses a 2-level min3 tree (depth 2) instead of the 7-deep serial fmin chain.
// Windows: level1 = 3, level2 = 9 >= 8 -> q_r = min(t_0..t_r) exactly (min is
// associative + idempotent; overlap is harmless). Scan is latency-bound on
// the per-column dependent chain (r19 ablation + r20/r21 deltas), so depth,
// not instruction count, is the lever.
__global__ __launch_bounds__(512, 1) void dtw_full(const float* __restrict__ x,
                                                   const float* __restrict__ y,
                                                   float* __restrict__ out)
{
    __shared__ unsigned short Dp[2][64][520];
    __shared__ float x2s[512], y2s[512];
    __shared__ float psum[64][68];     // row stride 272B: 16B-aligned for b128

    const int b   = blockIdx.x;
    const int tid = threadIdx.x;
    const int w   = tid >> 6;
    const int l   = tid & 63;
    const int lr  = l & 15;
    const int lg  = l >> 4;

    const float* xb = x + (size_t)b * 512 * 64;
    const float* yb = y + (size_t)b * 512 * 64;

    {
        const float4* xr = reinterpret_cast<const float4*>(xb + (size_t)tid * 64);
        const float4* yr = reinterpret_cast<const float4*>(yb + (size_t)tid * 64);
        float sx = 0.f, sy = 0.f;
        #pragma unroll
        for (int q = 0; q < 16; ++q) {
            float4 vx = xr[q], vy = yr[q];
            sx += vx.x*vx.x + vx.y*vx.y + vx.z*vx.z + vx.w*vx.w;
            sy += vy.x*vy.x + vy.y*vy.y + vy.z*vy.z + vy.w*vy.w;
        }
        x2s[tid] = sx;
        y2s[tid] = sy;
    }
    __syncthreads();

    const int ntile = (w == 6) ? 2 : 1;
    float cs[2][16];

    auto produce = [&](int pp) {
        const int j0 = pp * 64;
        unsigned short (*DBw)[520] = Dp[pp & 1];
        #pragma unroll
        for (int it = 0; it < 2; ++it) {
            if (it < ntile) {
                const int rt = (it == 0) ? w : 7;
                short8 afr[4][2];
                #pragma unroll
                for (int mi = 0; mi < 4; ++mi)
                    #pragma unroll
                    for (int ks = 0; ks < 2; ++ks) {
                        const float* rp = xb + (size_t)(rt*64 + mi*16 + lr) * 64 + ks*32 + lg*8;
                        float4 a0 = *reinterpret_cast<const float4*>(rp);
                        float4 a1 = *reinterpret_cast<const float4*>(rp + 4);
                        afr[mi][ks] = make_frag(a0, a1);
                    }
                f32x4 acc[4][4] = {};
                #pragma unroll
                for (int ni = 0; ni < 4; ++ni) {
                    const float* rp = yb + (size_t)(j0 + ni*16 + lr) * 64 + lg*8;
                    float4 b0 = *reinterpret_cast<const float4*>(rp);
                    float4 b1 = *reinterpret_cast<const float4*>(rp + 4);
                    float4 b2 = *reinterpret_cast<const float4*>(rp + 32);
                    float4 b3 = *reinterpret_cast<const float4*>(rp + 36);
                    short8 bf0 = make_frag(b0, b1);
                    short8 bf1 = make_frag(b2, b3);
                    #pragma unroll
                    for (int mi = 0; mi < 4; ++mi) {
                        acc[mi][ni] = __builtin_amdgcn_mfma_f32_16x16x32_bf16(afr[mi][0], bf0, acc[mi][ni], 0, 0, 0);
                        acc[mi][ni] = __builtin_amdgcn_mfma_f32_16x16x32_bf16(afr[mi][1], bf1, acc[mi][ni], 0, 0, 0);
                    }
                }
                float4 x2q[4];
                #pragma unroll
                for (int mi = 0; mi < 4; ++mi)
                    x2q[mi] = *reinterpret_cast<const float4*>(&x2s[rt*64 + mi*16 + lg*4]);
                #pragma unroll
                for (int ni = 0; ni < 4; ++ni) {
                    float y2v = y2s[j0 + ni*16 + lr];
                    #pragma unroll
                    for (int mi = 0; mi < 4; ++mi) {
                        float dd0 = x2q[mi].x + y2v - 2.0f * acc[mi][ni][0];
                        float dd1 = x2q[mi].y + y2v - 2.0f * acc[mi][ni][1];
                        float dd2 = x2q[mi].z + y2v - 2.0f * acc[mi][ni][2];
                        float dd3 = x2q[mi].w + y2v - 2.0f * acc[mi][ni][3];
                        unsigned w0 = pk_bf16(dd0, dd1);
                        unsigned w1 = pk_bf16(dd2, dd3);
                        uint2 pw; pw.x = w0; pw.y = w1;
                        *reinterpret_cast<uint2*>(&DBw[ni*16 + lr][rt*64 + mi*16 + lg*4]) = pw;
                        float fa = __uint_as_float(w0 << 16);
                        float fb = __uint_as_float(w0 & 0xffff0000u);
                        float fc = __uint_as_float(w1 << 16);
                        float fd = __uint_as_float(w1 & 0xffff0000u);
                        float s4 = (fa + fb) + (fc + fd);
                        s4 += __shfl_xor(s4, 16);
                        cs[it][mi*4 + ni] = s4;
                    }
                }
            }
        }
    };

    if (w < 7) produce(0);

    float pR[8];
    #pragma unroll
    for (int r = 0; r < 8; ++r) pR[r] = BIG;
    float bnd  = BIG;
    float bigf = BIG;

    #pragma unroll 1
    for (int p = 0; p < 8; ++p) {
        if (w < 7) {
            #pragma unroll
            for (int it = 0; it < 2; ++it) {
                if (it < ntile) {
                    const int rt = (it == 0) ? w : 7;
                    #pragma unroll
                    for (int mi = 0; mi < 4; ++mi)
                        #pragma unroll
                        for (int ni = 0; ni < 4; ++ni)
                            if ((lg & 1) == 0)
                                psum[ni*16 + lr][rt*8 + mi*2 + (lg >> 1)] = cs[it][mi*4 + ni];
                }
            }
        }
        __syncthreads();

        if (w == 7) {
            __builtin_amdgcn_s_setprio(1);
            // vectorized exclusive group-prefix per column (lane = column)
            {
                float4 v[16];
                #pragma unroll
                for (int q4 = 0; q4 < 16; ++q4)
                    v[q4] = *reinterpret_cast<const float4*>(&psum[l][q4*4]);
                float run = 0.f;
                #pragma unroll
                for (int q4 = 0; q4 < 16; ++q4) {
                    float a0 = v[q4].x, a1 = v[q4].y, a2 = v[q4].z, a3 = v[q4].w;
                    float r1s = run + a0, r2s = r1s + a1, r3s = r2s + a2;
                    v[q4].x = run; v[q4].y = r1s; v[q4].z = r2s; v[q4].w = r3s;
                    run = r3s + a3;
                }
                #pragma unroll
                for (int q4 = 0; q4 < 16; ++q4)
                    *reinterpret_cast<float4*>(&psum[l][q4*4]) = v[q4];
            }
            const unsigned short* DB = &Dp[p & 1][0][0];

            float S0, S1, S2, S3, S4, S5, S6, S7, P;
            auto buildS = [&](uint4 dc, float pex) {
                P  = pex;
                S0 = pex + __uint_as_float(dc.x << 16);
                S1 = S0  + __uint_as_float(dc.x & 0xffff0000u);
                S2 = S1  + __uint_as_float(dc.y << 16);
                S3 = S2  + __uint_as_float(dc.y & 0xffff0000u);
                S4 = S3  + __uint_as_float(dc.z << 16);
                S5 = S4  + __uint_as_float(dc.z & 0xffff0000u);
                S6 = S5  + __uint_as_float(dc.w << 16);
                S7 = S6  + __uint_as_float(dc.w & 0xffff0000u);
            };

            uint4 dcA  = *reinterpret_cast<const uint4*>(DB + l*8);
            float pexA = psum[0][l];
            uint4 dcB  = *reinterpret_cast<const uint4*>(DB + 520 + l*8);
            float pexB = psum[1][l];
            buildS(dcA, pexA);              // S for column 0

            #pragma unroll 1
            for (int cl = 0; cl < 64; ++cl) {
                const int cl2 = (cl < 62) ? cl + 2 : 63;
                uint4 dc2  = *reinterpret_cast<const uint4*>(DB + cl2*520 + l*8);
                float pex2 = psum[cl2][l];

                // ---- chain on current column's S (critical path) ----
                float cz  = (p == 0 && cl == 0) ? 0.0f : BIG;
                float b0v = (l == 0) ? cz : bnd;
                float t0 = fminf(b0v,  pR[0]) - P;
                float t1 = fminf(pR[0], pR[1]) - S0;
                float t2 = fminf(pR[1], pR[2]) - S1;
                float t3 = fminf(pR[2], pR[3]) - S2;
                float t4 = fminf(pR[3], pR[4]) - S3;
                float t5 = fminf(pR[4], pR[5]) - S4;
                float t6 = fminf(pR[5], pR[6]) - S5;
                float t7 = fminf(pR[6], pR[7]) - S6;

                // inclusive prefix-min, 2-level min3 tree (depth 2)
                float u0 = t0;
                float u1 = fminf(t1, t0);
                float u2 = min3f(t2, t1, t0);
                float u3 = min3f(t3, t2, t1);
                float u4 = min3f(t4, t3, t2);
                float u5 = min3f(t5, t4, t3);
                float u6 = min3f(t6, t5, t4);
                float u7 = min3f(t7, t6, t5);
                float q0 = u0;
                float q1 = u1;
                float q2 = u2;
                float q3 = fminf(u3, u0);
                float q4 = fminf(u4, u1);
                float q5 = fminf(u5, u2);
                float q6 = min3f(u6, u3, u0);
                float q7 = min3f(u7, u4, u1);

                float v = q7;
                DPPMIN(v, 0x111, 0xf);   // row_shr:1
                DPPMIN(v, 0x112, 0xf);   // row_shr:2
                DPPMIN(v, 0x114, 0xf);   // row_shr:4
                DPPMIN(v, 0x118, 0xf);   // row_shr:8
                DPPMIN(v, 0x142, 0xa);   // row_bcast:15
                DPPMIN(v, 0x143, 0xc);   // row_bcast:31
                float e = dpp_shr1_old(v, bigf);   // exclusive, lane0 = BIG

                float nR0 = S0 + fminf(e, q0);
                float nR1 = S1 + fminf(e, q1);
                float nR2 = S2 + fminf(e, q2);
                float nR3 = S3 + fminf(e, q3);
                float nR4 = S4 + fminf(e, q4);
                float nR5 = S5 + fminf(e, q5);
                float nR6 = S6 + fminf(e, q6);
                float nR7 = S7 + fminf(e, q7);

                // ---- off-chain: next column's S; rotate prefetch ----
                buildS(dcB, pexB);
                dcB = dc2; pexB = pex2;

                pR[0] = nR0; pR[1] = nR1; pR[2] = nR2; pR[3] = nR3;
                pR[4] = nR4; pR[5] = nR5; pR[6] = nR6; pR[7] = nR7;
                bnd = dpp_shr1_old(nR7, nR7);
            }
            __builtin_amdgcn_s_setprio(0);
        } else if (p < 7) {
            produce(p + 1);
        }
        __syncthreads();
    }

    if (w == 7 && l == 63) out[b] = pR[7];
}

extern "C" void kernel_launch(void* const* d_in, const int* in_sizes, int n_in,
                              void* d_out, int out_size, void* d_ws, size_t ws_size,
                              hipStream_t stream) {
    (void)in_sizes; (void)n_in; (void)d_ws; (void)ws_size; (void)out_size;
    const float* x = (const float*)d_in[0];
    const float* y = (const float*)d_in[1];
    float* out = (float*)d_out;
    dtw_full<<<128, 512, 0, stream>>>(x, y, out);
}